// Round 2
// baseline (81.797 us; speedup 1.0000x reference)
//
#include <hip/hip_runtime.h>

namespace {
constexpr int kBS = 8, kNV = 16, kNP = 8, kNR = 12;
constexpr int kRelCell = 288;          // NP*K*NR floats per (b,v,f,t) cell
constexpr int kH = 64, kNOUT = 64;
constexpr int CELLS  = 8;              // cells per wave
constexpr int WAVES  = 4;
constexpr int CPB    = WAVES * CELLS;  // 32 cells per block
constexpr int CHUNKS = 256 / CPB;      // 8 blocks per (b,v)
constexpr int WT_LD  = 65;             // padded leading dim: conflict-free
}

__device__ __forceinline__ float readlane_f(float v, int l) {
    union { float f; int i; } u; u.f = v;
    u.i = __builtin_amdgcn_readlane(u.i, l);
    return u.f;
}

// grid: 128 (b,v) * 8 chunks = 1024 blocks of 256 threads (4 waves).
// Each wave owns 8 consecutive-t cells -> its rel data is one contiguous
// 9.2 KB stream. Depth-2 register prefetch hides HBM latency.
__global__ __launch_bounds__(256, 4) void gal_kernel(
    const float* __restrict__ rel,      // (BS,NV,MF,MT,NP,K,NR)
    const float* __restrict__ se,       // (BS,NV,MT,MF,H)
    const float* __restrict__ s,        // (BS,NV,NOUT)
    const float* __restrict__ Wstack,   // (NR,H,H)
    const float* __restrict__ lin_w,    // (1,H+NOUT)
    const float* __restrict__ lin_b,    // (1,)
    const float* __restrict__ out_w,    // (NOUT,H)
    const float* __restrict__ out_b,    // (NOUT,)
    float* __restrict__ out)            // (BS,NV,NOUT)
{
    __shared__ __align__(16) float wT[kH * WT_LD];          // 16.6 KB
    __shared__ __align__(16) float relbuf[WAVES][kRelCell]; // 4.6 KB

    const int tid  = (int)threadIdx.x;
    const int lane = tid & 63;
    const int w    = tid >> 6;

    // out_w (o,d) -> wT[d*65+o]. Writes: lanes stride 65 floats -> distinct
    // banks; reads (global) coalesced.
    for (int i = tid; i < kH * kNOUT; i += 256) {
        const int o = i >> 6, d = i & 63;
        wT[d * WT_LD + o] = out_w[i];
    }

    const int bv    = (int)blockIdx.x / CHUNKS;
    const int chunk = (int)blockIdx.x % CHUNKS;

    // lane = d constants
    float dreg[kNR];
#pragma unroll
    for (int r = 0; r < kNR; ++r)
        dreg[r] = Wstack[r * kH * kH + lane * (kH + 1)];
    const float wz = lin_w[kNOUT + lane];
    float sv = s[bv * kNOUT + lane] * lin_w[lane];
#pragma unroll
    for (int m = 1; m < 64; m <<= 1) sv += __shfl_xor(sv, m, 64);
    const float logit_base = sv + lin_b[0];
    const float ob = out_b[lane];   // lane = o in epilogue

    // wave's 8 cells: c = c0..c0+7, t = c&15 (inner), f = c>>4 (same for all 8)
    const int c0 = chunk * CPB + w * CELLS;
    const int f0 = c0 >> 4;
    const int t0 = c0 & 15;
    const float* relp = rel + ((size_t)(bv * 16 + f0) * 16 + t0) * kRelCell;
    const float* sep  = se + ((size_t)(bv * 16 + t0) * 16 + f0) * kH + lane;
    // se stride between consecutive t: 16*64 floats
    constexpr size_t SE_T = 16 * kH;

    // depth-2 prefetch: issue cells 0 and 1 now
    float pfA[5], pfB[5], sevA, sevB;
    {
        const float* rp = relp;
#pragma unroll
        for (int j = 0; j < 4; ++j) pfA[j] = rp[lane + j * 64];
        pfA[4] = (lane < 32) ? rp[256 + lane] : 0.f;
        sevA = sep[0];
    }
    {
        const float* rp = relp + kRelCell;
#pragma unroll
        for (int j = 0; j < 4; ++j) pfB[j] = rp[lane + j * 64];
        pfB[4] = (lane < 32) ? rp[256 + lane] : 0.f;
        sevB = sep[SE_T];
    }

    __syncthreads();  // wT ready
    float* rb = &relbuf[w][0];
    float zreg[CELLS];

#pragma unroll
    for (int i = 0; i < CELLS; ++i) {
        float sev;
        if ((i & 1) == 0) {
            sev = sevA;
#pragma unroll
            for (int j = 0; j < 4; ++j) rb[lane + j * 64] = pfA[j];
            if (lane < 32) rb[256 + lane] = pfA[4];
            if (i + 2 < CELLS) {
                const float* rp = relp + (size_t)(i + 2) * kRelCell;
#pragma unroll
                for (int j = 0; j < 4; ++j) pfA[j] = rp[lane + j * 64];
                pfA[4] = (lane < 32) ? rp[256 + lane] : 0.f;
                sevA = sep[(size_t)(i + 2) * SE_T];
            }
        } else {
            sev = sevB;
#pragma unroll
            for (int j = 0; j < 4; ++j) rb[lane + j * 64] = pfB[j];
            if (lane < 32) rb[256 + lane] = pfB[4];
            if (i + 2 < CELLS) {
                const float* rp = relp + (size_t)(i + 2) * kRelCell;
#pragma unroll
                for (int j = 0; j < 4; ++j) pfB[j] = rp[lane + j * 64];
                pfB[4] = (lane < 32) ? rp[256 + lane] : 0.f;
                sevB = sep[(size_t)(i + 2) * SE_T];
            }
        }

        float zj[kNP], lg[kNP];
#pragma unroll
        for (int p = 0; p < kNP; ++p) {
            const float4* r4 = (const float4*)(rb + p * 36);
            const float4 a0 = r4[0], a1 = r4[1], a2 = r4[2];
            const float4 b0 = r4[3], b1 = r4[4], b2 = r4[5];
            const float4 c0v = r4[6], c1 = r4[7], c2 = r4[8];
            float d0 = a0.x*dreg[0] + a0.y*dreg[1] + a0.z*dreg[2] + a0.w*dreg[3]
                     + a1.x*dreg[4] + a1.y*dreg[5] + a1.z*dreg[6] + a1.w*dreg[7]
                     + a2.x*dreg[8] + a2.y*dreg[9] + a2.z*dreg[10] + a2.w*dreg[11];
            float d1 = b0.x*dreg[0] + b0.y*dreg[1] + b0.z*dreg[2] + b0.w*dreg[3]
                     + b1.x*dreg[4] + b1.y*dreg[5] + b1.z*dreg[6] + b1.w*dreg[7]
                     + b2.x*dreg[8] + b2.y*dreg[9] + b2.z*dreg[10] + b2.w*dreg[11];
            float d2 = c0v.x*dreg[0] + c0v.y*dreg[1] + c0v.z*dreg[2] + c0v.w*dreg[3]
                     + c1.x*dreg[4] + c1.y*dreg[5] + c1.z*dreg[6] + c1.w*dreg[7]
                     + c2.x*dreg[8] + c2.y*dreg[9] + c2.z*dreg[10] + c2.w*dreg[11];
            const float z = d0 * d1 * d2 * sev;
            zj[p] = z;
            float la = z * wz;
#pragma unroll
            for (int m = 1; m < 64; m <<= 1) la += __shfl_xor(la, m, 64);
            lg[p] = la + logit_base;
        }

        float mx = lg[0];
#pragma unroll
        for (int p = 1; p < kNP; ++p) mx = fmaxf(mx, lg[p]);
        float e[kNP], esum = 0.f;
#pragma unroll
        for (int p = 0; p < kNP; ++p) { e[p] = __expf(lg[p] - mx); esum += e[p]; }
        const float inv = 1.0f / esum;
        float zd = 0.f;
#pragma unroll
        for (int p = 0; p < kNP; ++p) zd = fmaf(e[p] * inv, zj[p], zd);
        zreg[i] = zd;
    }

    // batched 64x64 matvec for the wave's 8 cells; lane = o
    float q[CELLS];
#pragma unroll
    for (int i = 0; i < CELLS; ++i) q[i] = 0.f;
#pragma unroll
    for (int d = 0; d < kH; ++d) {
        const float wv = wT[d * WT_LD + lane];
#pragma unroll
        for (int i = 0; i < CELLS; ++i)
            q[i] = fmaf(readlane_f(zreg[i], d), wv, q[i]);
    }
    float tot = 0.f;
#pragma unroll
    for (int i = 0; i < CELLS; ++i) tot += fmaxf(q[i] + ob, 0.f);

    // block-level reduce -> single wave-atomic per block
    __syncthreads();
    ((float*)relbuf)[w * 64 + lane] = tot;
    __syncthreads();
    if (w == 0) {
        const float* rr = (const float*)relbuf;
        const float r = rr[lane] + rr[64 + lane] + rr[128 + lane] + rr[192 + lane];
        atomicAdd(&out[bv * kNOUT + lane], r);
    }
}

extern "C" void kernel_launch(void* const* d_in, const int* in_sizes, int n_in,
                              void* d_out, int out_size, void* d_ws, size_t ws_size,
                              hipStream_t stream) {
    const float* rel   = (const float*)d_in[0];
    const float* sem   = (const float*)d_in[1];
    const float* s     = (const float*)d_in[2];
    const float* Wst   = (const float*)d_in[3];
    const float* lin_w = (const float*)d_in[4];
    const float* lin_b = (const float*)d_in[5];
    const float* out_w = (const float*)d_in[6];
    const float* out_b = (const float*)d_in[7];
    float* out = (float*)d_out;

    hipMemsetAsync(out, 0, sizeof(float) * kBS * kNV * kNOUT, stream);
    dim3 grid(kBS * kNV * CHUNKS), block(256);
    hipLaunchKernelGGL(gal_kernel, grid, block, 0, stream,
                       rel, sem, s, Wst, lin_w, lin_b, out_w, out_b, out);
}